// Round 9
// baseline (80.873 us; speedup 1.0000x reference)
//
#include <hip/hip_runtime.h>
#include <math.h>

#define ALPHA 0.2f

constexpr int BB   = 4;
constexpr int NN_  = 4096;
constexpr int HN   = 2048;      // N/2
constexpr int FIN  = 128;
constexpr int FF   = 64;
constexpr int ROWS = BB * NN_;  // 16384
constexpr int NBLK = 256;       // == CU count; all blocks co-resident by construction

// ---- workspace layout (float offsets) ----
constexpr size_t WS_H    = 0;                          // ROWS*FF  h matrix (4 MB)
constexpr size_t WS_C    = (size_t)ROWS * FF;          // ROWS     c = s1+s2 per row
constexpr size_t WS_E    = WS_C + ROWS;                // ROWS     e = even? s1 : s2
constexpr size_t WS_A0   = WS_E + ROWS;                // BB*FF
constexpr size_t WS_A1   = WS_A0 + (size_t)BB * FF;    // BB*FF
constexpr size_t WS_U    = WS_A1 + (size_t)BB * FF;    // BB*FF
constexpr size_t WS_M    = WS_U + (size_t)BB * FF;     // 2*BB  (M0,M1 per batch)
constexpr size_t WS_WQ   = WS_M + 2 * BB;              // BB*HN*4  weight table (float4/jp)
constexpr size_t WS_SYNC = WS_WQ + (size_t)BB * HN * 4; // 3 ints (barrier counters)

// Manual grid barrier: all 256 blocks are resident (grid == CU count), so the
// spin always completes. __syncthreads drains each wave's stores; tid0's
// __threadfence is an agent-scope fence crossing the non-coherent per-XCD L2s.
__device__ __forceinline__ void gbar(int* cnt, int tid) {
  __syncthreads();
  if (tid == 0) {
    __threadfence();                 // release
    atomicAdd(cnt, 1);
    while (atomicAdd(cnt, 0) < NBLK) __builtin_amdgcn_s_sleep(2);
    __threadfence();                 // acquire
  }
  __syncthreads();
}

__global__ __launch_bounds__(256) void fused(const float* __restrict__ inp,
                                             const float* __restrict__ W,
                                             const float* __restrict__ a,
                                             float* __restrict__ ws,
                                             float* __restrict__ out) {
  const int tid  = threadIdx.x;
  const int lane = tid & 63;
  const int wv   = __builtin_amdgcn_readfirstlane(tid >> 6);
  const int blk  = blockIdx.x;
  int* cnt = (int*)(ws + WS_SYNC);

  __shared__ float rows_s[64 * FIN];   // 32 KB
  __shared__ float redm[4][2];
  __shared__ float accbuf[4][2][64];

  // ================= Phase A: h = inp @ W + per-row dots c,e =================
  {
    float Wreg[FIN];
    #pragma unroll
    for (int k = 0; k < FIN; ++k) Wreg[k] = W[k * FF + lane];
    const float a1 = a[lane];
    const float a2 = a[FF + lane];
    const float asum = a1 + a2;

    const int rowbase = blk * 64;
    const float4* src = reinterpret_cast<const float4*>(inp + (size_t)rowbase * FIN);
    float4* dst = reinterpret_cast<float4*>(rows_s);
    #pragma unroll
    for (int i = 0; i < 8; ++i) dst[tid + i * 256] = src[tid + i * 256];
    __syncthreads();

    // zero ALL 3*BB*FF = 768 accumulator floats (3 blocks x 256 threads).
    // Replay-safe: atomics in phase C would otherwise accumulate across calls.
    if (blk < 3) ws[WS_A0 + (size_t)blk * 256 + tid] = 0.f;

    float* hout = ws + WS_H;
    float* cout = ws + WS_C;
    float* eout = ws + WS_E;

    for (int p = 0; p < 8; ++p) {
      const int lr0 = wv * 16 + 2 * p;              // local even row
      const float* rp0 = rows_s + lr0 * FIN;
      const float* rp1 = rp0 + FIN;
      float h0 = 0.f, h0b = 0.f, h1 = 0.f, h1b = 0.f;
      #pragma unroll
      for (int k = 0; k < FIN; k += 4) {
        const float4 x0 = *reinterpret_cast<const float4*>(rp0 + k);
        const float4 x1 = *reinterpret_cast<const float4*>(rp1 + k);
        h0  = fmaf(x0.x, Wreg[k],     h0);
        h0b = fmaf(x0.y, Wreg[k + 1], h0b);
        h0  = fmaf(x0.z, Wreg[k + 2], h0);
        h0b = fmaf(x0.w, Wreg[k + 3], h0b);
        h1  = fmaf(x1.x, Wreg[k],     h1);
        h1b = fmaf(x1.y, Wreg[k + 1], h1b);
        h1  = fmaf(x1.z, Wreg[k + 2], h1);
        h1b = fmaf(x1.w, Wreg[k + 3], h1b);
      }
      const float H0 = h0 + h0b;
      const float H1 = h1 + h1b;
      const int r0 = rowbase + lr0;
      hout[(size_t)r0 * FF + lane] = H0;
      hout[(size_t)(r0 + 1) * FF + lane] = H1;

      float c0 = H0 * asum, e0 = H0 * a1;   // even row -> s1
      float c1 = H1 * asum, e1 = H1 * a2;   // odd row  -> s2
      #pragma unroll
      for (int s = 32; s >= 1; s >>= 1) {
        c0 += __shfl_xor(c0, s, 64);
        e0 += __shfl_xor(e0, s, 64);
        c1 += __shfl_xor(c1, s, 64);
        e1 += __shfl_xor(e1, s, 64);
      }
      if (lane == 0) {
        cout[r0] = c0;     eout[r0] = e0;
        cout[r0 + 1] = c1; eout[r0 + 1] = e1;
      }
    }
  }
  gbar(cnt + 0, tid);

  // ================= Phase B: stats + weight table (blocks 0..31) =================
  if (blk < 32) {
    const int b = blk >> 3, slice = blk & 7;
    const float* c = ws + WS_C + (size_t)b * NN_;
    const float* e = ws + WS_E + (size_t)b * NN_;

    float lv[16];
    float me = -INFINITY, mo = -INFINITY;
    #pragma unroll
    for (int i = 0; i < 4; ++i) {
      const float4 cv = reinterpret_cast<const float4*>(c)[tid + i * 256];
      const float l0 = cv.x > 0.f ? cv.x : ALPHA * cv.x;
      const float l1 = cv.y > 0.f ? cv.y : ALPHA * cv.y;
      const float l2 = cv.z > 0.f ? cv.z : ALPHA * cv.z;
      const float l3 = cv.w > 0.f ? cv.w : ALPHA * cv.w;
      lv[4*i] = l0; lv[4*i+1] = l1; lv[4*i+2] = l2; lv[4*i+3] = l3;
      me = fmaxf(me, fmaxf(l0, l2));
      mo = fmaxf(mo, fmaxf(l1, l3));
    }
    #pragma unroll
    for (int s = 32; s >= 1; s >>= 1) {
      me = fmaxf(me, __shfl_xor(me, s, 64));
      mo = fmaxf(mo, __shfl_xor(mo, s, 64));
    }
    if (lane == 0) { redm[wv][0] = me; redm[wv][1] = mo; }
    __syncthreads();
    const float M0 = fmaxf(fmaxf(redm[0][0], redm[1][0]), fmaxf(redm[2][0], redm[3][0]));
    const float M1 = fmaxf(fmaxf(redm[0][1], redm[1][1]), fmaxf(redm[2][1], redm[3][1]));
    __syncthreads();

    float se = 0.f, so = 0.f;
    #pragma unroll
    for (int i = 0; i < 4; ++i) {
      se += __expf(lv[4*i]     - M0) + __expf(lv[4*i+2] - M0);
      so += __expf(lv[4*i + 1] - M1) + __expf(lv[4*i+3] - M1);
    }
    #pragma unroll
    for (int s = 32; s >= 1; s >>= 1) {
      se += __shfl_xor(se, s, 64);
      so += __shfl_xor(so, s, 64);
    }
    if (lane == 0) { redm[wv][0] = se; redm[wv][1] = so; }
    __syncthreads();
    const float P0 = redm[0][0] + redm[1][0] + redm[2][0] + redm[3][0];
    const float P1 = redm[0][1] + redm[1][1] + redm[2][1] + redm[3][1];

    // weight-table entry: 1 jp per thread
    const int jp = slice * 256 + tid;
    const float2 ev = reinterpret_cast<const float2*>(e)[jp];
    const float d = ev.x + ev.y;
    const float v = d > 0.f ? d : ALPHA * d;
    const float m0 = fmaxf(M0, v), m1 = fmaxf(M1, v);
    const float eM0 = __expf(M0 - m0), ev0 = __expf(v - m0);
    const float eM1 = __expf(M1 - m1), ev1 = __expf(v - m1);
    const float Z0 = eM0 * P0 + (float)HN * ev0;
    const float Z1 = eM1 * P1 + (float)HN * ev1;
    reinterpret_cast<float4*>(ws + WS_WQ)[(size_t)b * HN + jp] =
        make_float4(eM0 / Z0, ev0 / Z0, eM1 / Z1, ev1 / Z1);

    if (slice == 0 && tid == 0) { ws[WS_M + 2*b] = M0; ws[WS_M + 2*b + 1] = M1; }
  }
  gbar(cnt + 1, tid);

  // ================= Phase C: weighted column sums =================
  {
    const int b   = blk >> 6;          // 64 blocks per batch
    const int seg = blk & 63;          // 64 rows per segment
    const float* h = ws + WS_H + (size_t)b * NN_ * FF;
    const float4* wq = reinterpret_cast<const float4*>(ws + WS_WQ) + (size_t)b * HN;

    const int j0 = seg * 64 + wv * 16;
    float accA = 0.f, accU = 0.f;
    #pragma unroll 8
    for (int r = 0; r < 16; ++r) {
      const int j = j0 + r;
      const float hv = h[(size_t)j * FF + lane];
      const float4 q = wq[j & (HN - 1)];
      const float qa = (seg < 32) ? q.x : q.z;
      const float qu = (seg < 32) ? q.y : q.w;
      accA = fmaf(qa, hv, accA);
      accU = fmaf(qu, hv, accU);
    }
    accbuf[wv][0][lane] = accA;
    accbuf[wv][1][lane] = accU;
    __syncthreads();
    if (tid < 64) {
      const float sA = accbuf[0][0][tid] + accbuf[1][0][tid] + accbuf[2][0][tid] + accbuf[3][0][tid];
      const float sU = accbuf[0][1][tid] + accbuf[1][1][tid] + accbuf[2][1][tid] + accbuf[3][1][tid];
      float* A = ws + ((seg < 32) ? WS_A0 : WS_A1) + (size_t)b * FF;
      atomicAdd(&A[tid], sA);
      atomicAdd(ws + WS_U + (size_t)b * FF + tid, sU);
    }
  }
  gbar(cnt + 2, tid);

  // ================= Phase D: rank-2 reconstruction + elu =================
  #pragma unroll
  for (int it = 0; it < 4; ++it) {
    const int idx = blk * 1024 + it * 256 + tid;   // float4 group, B*N*16 total
    const int b   = idx >> 16;
    const int rem = idx & 65535;
    const int i   = rem >> 4;
    const int fg  = rem & 15;
    float4 v;
    if (i < HN) {
      const float* c = ws + WS_C + (size_t)b * NN_;
      const float M0 = ws[WS_M + 2 * b];
      const float M1 = ws[WS_M + 2 * b + 1];
      float c0 = c[2 * i], c1 = c[2 * i + 1];
      c0 = c0 > 0.f ? c0 : ALPHA * c0;
      c1 = c1 > 0.f ? c1 : ALPHA * c1;
      const float al = __expf(c0 - M0);
      const float be = __expf(c1 - M1);
      const float4 A0v = reinterpret_cast<const float4*>(ws + WS_A0 + (size_t)b * FF)[fg];
      const float4 A1v = reinterpret_cast<const float4*>(ws + WS_A1 + (size_t)b * FF)[fg];
      v.x = al * A0v.x + be * A1v.x;
      v.y = al * A0v.y + be * A1v.y;
      v.z = al * A0v.z + be * A1v.z;
      v.w = al * A0v.w + be * A1v.w;
    } else {
      v = reinterpret_cast<const float4*>(ws + WS_U + (size_t)b * FF)[fg];
    }
    v.x = v.x > 0.f ? v.x : expm1f(v.x);
    v.y = v.y > 0.f ? v.y : expm1f(v.y);
    v.z = v.z > 0.f ? v.z : expm1f(v.z);
    v.w = v.w > 0.f ? v.w : expm1f(v.w);
    reinterpret_cast<float4*>(out)[idx] = v;
  }
}

extern "C" void kernel_launch(void* const* d_in, const int* in_sizes, int n_in,
                              void* d_out, int out_size, void* d_ws, size_t ws_size,
                              hipStream_t stream) {
  (void)in_sizes; (void)n_in; (void)out_size; (void)ws_size;
  const float* inp = (const float*)d_in[0];
  const float* W   = (const float*)d_in[1];
  const float* a   = (const float*)d_in[2];
  float* out = (float*)d_out;
  float* ws  = (float*)d_ws;

  // zero the 3 barrier counters (stream-ordered, graph-capture-legal)
  hipMemsetAsync((char*)d_ws + WS_SYNC * sizeof(float), 0, 64, stream);
  hipLaunchKernelGGL(fused, dim3(NBLK), dim3(256), 0, stream, inp, W, a, ws, out);
}